// Round 11
// baseline (568.463 us; speedup 1.0000x reference)
//
#include <hip/hip_runtime.h>
#include <math.h>

#define NN 50000
#define NE 600000
#define DIM 128
#define LAYERS 3
#define BN_EPS 1e-5f

#define SC_ELE 2048
#define NSCAN ((NN + SC_ELE - 1) / SC_ELE)   // 25 scan blocks
#define TM 32

typedef short bfrag8 __attribute__((ext_vector_type(8)));   // 8 bf16 = 4 VGPR
typedef float facc4 __attribute__((ext_vector_type(4)));    // MFMA C/D

// fp32 -> bf16 round-to-nearest-even (scalar in/out: no scratch risk)
__device__ __forceinline__ unsigned short f2bf(float f) {
    union { float f; unsigned u; } x; x.f = f;
    unsigned r = x.u + 0x7fff + ((x.u >> 16) & 1);
    return (unsigned short)(r >> 16);
}

// ---------------------------------------------------------------- init ----
__global__ void k_init(int* __restrict__ deg, float* __restrict__ bnstats) {
    int i = blockIdx.x * 256 + threadIdx.x;
    if (i < NN) deg[i] = 0;
    if (i < LAYERS * 2 * DIM) bnstats[i] = 0.0f;
}

// ------------------- W -> bf16, transposed: Wt[l][m][n][k], once/call ----
__global__ void k_wconv(const float* __restrict__ W1, const float* __restrict__ W2,
                        unsigned short* __restrict__ Wt) {
    int id = blockIdx.x * 256 + threadIdx.x;     // LAYERS*2*128*128 = 98304
    if (id >= LAYERS * 2 * DIM * DIM) return;
    int n = id & 127, k = (id >> 7) & 127, m = (id >> 14) & 1, l = id >> 15;
    const float* W = (m ? W2 : W1) + (size_t)l * DIM * DIM;
    Wt[(size_t)((l * 2 + m) * DIM + n) * DIM + k] = f2bf(W[k * DIM + n]);
}

// ----------------------------------------------------------- histogram ----
__global__ void k_hist(const int* __restrict__ dst, int* __restrict__ deg) {
    int e = blockIdx.x * 256 + threadIdx.x;
    if (e < NE) atomicAdd(&deg[dst[e]], 1);
}

// ------------------------------------------- hierarchical scan, pass 1 ----
__global__ __launch_bounds__(1024) void k_scan1(const int* __restrict__ deg,
                                                int* __restrict__ part,
                                                int* __restrict__ bsum) {
    __shared__ int ws[16];
    const int t = threadIdx.x, lane = t & 63, wv = t >> 6;
    const int base = blockIdx.x * SC_ELE;
    const int e0 = base + 2 * t, e1 = e0 + 1;
    const int v0 = (e0 < NN) ? deg[e0] : 0;
    const int v1 = (e1 < NN) ? deg[e1] : 0;
    const int s = v0 + v1;
    int incl = s;
    #pragma unroll
    for (int o = 1; o < 64; o <<= 1) {
        int u = __shfl_up(incl, o);
        if (lane >= o) incl += u;
    }
    if (lane == 63) ws[wv] = incl;
    __syncthreads();
    if (wv == 0) {
        int x = (lane < 16) ? ws[lane] : 0;
        int ix = x;
        #pragma unroll
        for (int o = 1; o < 16; o <<= 1) {
            int u = __shfl_up(ix, o);
            if (lane >= o) ix += u;
        }
        if (lane < 16) ws[lane] = ix - x;          // exclusive wave offsets
        if (lane == 15) bsum[blockIdx.x] = ix;     // block total
    }
    __syncthreads();
    const int excl = incl - s + ws[wv];
    if (e0 < NN) part[e0] = excl;
    if (e1 < NN) part[e1] = excl + v0;
}

// ------------------------------------------- hierarchical scan, pass 2 ----
__global__ void k_scan2(const int* __restrict__ bsum, int* __restrict__ boff) {
    const int lane = threadIdx.x;                   // 64 threads, 1 block
    const int v = (lane < NSCAN) ? bsum[lane] : 0;
    int ix = v;
    #pragma unroll
    for (int o = 1; o < 64; o <<= 1) {
        int u = __shfl_up(ix, o);
        if (lane >= o) ix += u;
    }
    if (lane < NSCAN) boff[lane] = ix - v;
}

// --------------------------- hierarchical scan, pass 3 (+cur, +off[NN]) ----
__global__ void k_scan3(const int* __restrict__ part, const int* __restrict__ boff,
                        int* __restrict__ off, int* __restrict__ cur) {
    int i = blockIdx.x * 256 + threadIdx.x;
    if (i < NN) {
        int o = part[i] + boff[i >> 11];
        off[i] = o;
        cur[i] = o;
        if (i == 0) off[NN] = NE;
    }
}

// ------------------------------------------------------------ csr fill ----
__global__ void k_fill(const int* __restrict__ src, const int* __restrict__ dst,
                       int* __restrict__ cur, int* __restrict__ csr) {
    int e = blockIdx.x * 256 + threadIdx.x;
    if (e < NE) {
        int p = atomicAdd(&cur[dst[e]], 1);
        csr[p] = src[e];
    }
}

// ---------------- aggregate: a = f(h) + sum_in f(h), f = norm+relu ------
template <int NORM>
__global__ __launch_bounds__(256) void k_agg(const float* __restrict__ h,
                                             const float* __restrict__ bnsum,
                                             const float* __restrict__ bnsq,
                                             const float* __restrict__ gamma,
                                             const float* __restrict__ beta,
                                             const int* __restrict__ off,
                                             const int* __restrict__ csr,
                                             float* __restrict__ a) {
    int wid  = (blockIdx.x * 256 + threadIdx.x) >> 6;
    int lane = threadIdx.x & 63;
    if (wid >= NN) return;

    float2 scv = make_float2(1.f, 0.f), shv = make_float2(0.f, 0.f);
    if (NORM) {
        const int j0 = lane * 2;
        const float invN = 1.0f / (float)NN;
        float mu0 = bnsum[j0] * invN;
        float mu1 = bnsum[j0 + 1] * invN;
        float k0 = rsqrtf(bnsq[j0] * invN - mu0 * mu0 + BN_EPS) * gamma[j0];
        float k1 = rsqrtf(bnsq[j0 + 1] * invN - mu1 * mu1 + BN_EPS) * gamma[j0 + 1];
        scv = make_float2(k0, k1);
        shv = make_float2(beta[j0] - mu0 * k0, beta[j0 + 1] - mu1 * k1);
    }

    const int start = off[wid], end = off[wid + 1];
    float2 v = *(const float2*)&h[(size_t)wid * DIM + lane * 2];
    float2 acc;
    if (NORM) {
        acc.x = fmaxf(fmaf(v.x, scv.x, shv.x), 0.f);
        acc.y = fmaxf(fmaf(v.y, scv.y, shv.y), 0.f);
    } else {
        acc = v;
    }
    int i = start;
    for (; i + 3 < end; i += 4) {           // 4 independent loads in flight
        int s0 = csr[i], s1 = csr[i + 1], s2 = csr[i + 2], s3 = csr[i + 3];
        float2 v0 = *(const float2*)&h[(size_t)s0 * DIM + lane * 2];
        float2 v1 = *(const float2*)&h[(size_t)s1 * DIM + lane * 2];
        float2 v2 = *(const float2*)&h[(size_t)s2 * DIM + lane * 2];
        float2 v3 = *(const float2*)&h[(size_t)s3 * DIM + lane * 2];
        if (NORM) {
            v0.x = fmaxf(fmaf(v0.x, scv.x, shv.x), 0.f);
            v0.y = fmaxf(fmaf(v0.y, scv.y, shv.y), 0.f);
            v1.x = fmaxf(fmaf(v1.x, scv.x, shv.x), 0.f);
            v1.y = fmaxf(fmaf(v1.y, scv.y, shv.y), 0.f);
            v2.x = fmaxf(fmaf(v2.x, scv.x, shv.x), 0.f);
            v2.y = fmaxf(fmaf(v2.y, scv.y, shv.y), 0.f);
            v3.x = fmaxf(fmaf(v3.x, scv.x, shv.x), 0.f);
            v3.y = fmaxf(fmaf(v3.y, scv.y, shv.y), 0.f);
        }
        acc.x += v0.x + v1.x + v2.x + v3.x;
        acc.y += v0.y + v1.y + v2.y + v3.y;
    }
    for (; i < end; ++i) {
        int s0 = csr[i];
        float2 v0 = *(const float2*)&h[(size_t)s0 * DIM + lane * 2];
        if (NORM) {
            v0.x = fmaxf(fmaf(v0.x, scv.x, shv.x), 0.f);
            v0.y = fmaxf(fmaf(v0.y, scv.y, shv.y), 0.f);
        }
        acc.x += v0.x;
        acc.y += v0.y;
    }
    *(float2*)&a[(size_t)wid * DIM + lane * 2] = acc;
}

// ---- swizzled LDS byte offsets (row stride 256 B would be 16-way bank
// ---- conflict on ds_read_b128; XOR bit-4 with row&7 spreads slots, G4) ----
#define ZA_OFF(ROW, COLBF) ((((ROW) * 256) + (COLBF) * 2) ^ (((ROW) & 7) << 4))
#define WT_OFF(N, K)       ((((N) * 256) + (K) * 2) ^ (((N) & 7) << 4))

// stage 32 KB of bf16 W^T (global, pre-transposed) into wt with swizzle
#define STAGE_WT(PTR)                                                        \
    {                                                                        \
        _Pragma("unroll")                                                    \
        for (int i_ = 0; i_ < 8; ++i_) {                                     \
            int id_ = t + i_ * 256;                                          \
            int n_ = id_ >> 4, kc_ = id_ & 15;                               \
            uint4 v_ = *(const uint4*)&(PTR)[n_ * DIM + kc_ * 8];            \
            *(uint4*)((char*)wt + WT_OFF(n_, kc_ * 8)) = v_;                 \
        }                                                                    \
    }

// one full-K GEMM for this wave's 32x32 output (2x2 MFMA tiles, 4 K-steps)
#define MFMA_GEMM()                                                          \
    {                                                                        \
        _Pragma("unroll")                                                    \
        for (int ks_ = 0; ks_ < 4; ++ks_) {                                  \
            int k0_ = ks_ * 32 + kg;                                         \
            bfrag8 a0_ = *(const bfrag8*)((char*)za + ZA_OFF(ar, k0_));      \
            bfrag8 a1_ = *(const bfrag8*)((char*)za + ZA_OFF(16 + ar, k0_)); \
            bfrag8 b0_ = *(const bfrag8*)((char*)wt + WT_OFF(nc0, k0_));     \
            bfrag8 b1_ = *(const bfrag8*)((char*)wt + WT_OFF(nc1, k0_));     \
            c00 = __builtin_amdgcn_mfma_f32_16x16x32_bf16(a0_, b0_, c00, 0, 0, 0); \
            c01 = __builtin_amdgcn_mfma_f32_16x16x32_bf16(a0_, b1_, c01, 0, 0, 0); \
            c10 = __builtin_amdgcn_mfma_f32_16x16x32_bf16(a1_, b0_, c10, 0, 0, 0); \
            c11 = __builtin_amdgcn_mfma_f32_16x16x32_bf16(a1_, b1_, c11, 0, 0, 0); \
        }                                                                    \
    }

// ---------- MFMA MLP: z = relu(zW1+b1)W2+b2 (bf16 operands, fp32 accum) ----
// 4 waves x (32 rows x 32 cols); A,B from swizzled bf16 LDS; storage fp32.
__global__ __launch_bounds__(256, 4) void k_mlp(float* __restrict__ z,
                                                const unsigned short* __restrict__ Wt,
                                                const float* __restrict__ b1,
                                                const float* __restrict__ b2,
                                                float* __restrict__ bnsum,
                                                float* __restrict__ bnsq) {
    __shared__ unsigned short za[TM * DIM];    //  8 KB bf16 A-tile (swizzled)
    __shared__ unsigned short wt[DIM * DIM];   // 32 KB bf16 W^T  (swizzled)
    const int t = threadIdx.x;
    const int lane = t & 63, wv = t >> 6;      // wave id 0..3
    const int row0 = blockIdx.x * TM;
    const int ar  = lane & 15;                 // A row / C col component
    const int kg  = (lane >> 4) * 8;           // k-group base (A/B frags)
    const int nc0 = wv * 32 + ar;              // B col, tn=0
    const int nc1 = nc0 + 16;                  // B col, tn=1
    const int rb  = (lane >> 4) * 4;           // C/D row base within tile

    // ---- stage za: z fp32 -> bf16 (coalesced read, swizzled LDS write) ----
    #pragma unroll
    for (int i = 0; i < 4; ++i) {
        int f4 = t + i * 256;
        int row = f4 >> 5, c4 = f4 & 31;
        int g = row0 + row;
        float4 v = make_float4(0.f, 0.f, 0.f, 0.f);
        if (g < NN) v = *(const float4*)&z[(size_t)g * DIM + c4 * 4];
        ushort4 pk;
        pk.x = f2bf(v.x); pk.y = f2bf(v.y); pk.z = f2bf(v.z); pk.w = f2bf(v.w);
        *(ushort4*)((char*)za + ZA_OFF(row, c4 * 4)) = pk;
    }
    STAGE_WT(Wt);                               // W1^T
    __syncthreads();

    facc4 c00 = {0.f, 0.f, 0.f, 0.f}, c01 = {0.f, 0.f, 0.f, 0.f};
    facc4 c10 = {0.f, 0.f, 0.f, 0.f}, c11 = {0.f, 0.f, 0.f, 0.f};

    // ---- GEMM1 ----
    MFMA_GEMM();
    __syncthreads();                            // za/wt reads done

    // ---- y1 = relu(c + b1) -> za (bf16, swizzled); stage W2^T ----
    {
        const float bA = b1[nc0], bB = b1[nc1];
        #pragma unroll
        for (int reg = 0; reg < 4; ++reg) {
            int r0 = rb + reg, r1 = 16 + rb + reg;
            *(unsigned short*)((char*)za + ZA_OFF(r0, nc0)) = f2bf(fmaxf(c00[reg] + bA, 0.f));
            *(unsigned short*)((char*)za + ZA_OFF(r0, nc1)) = f2bf(fmaxf(c01[reg] + bB, 0.f));
            *(unsigned short*)((char*)za + ZA_OFF(r1, nc0)) = f2bf(fmaxf(c10[reg] + bA, 0.f));
            *(unsigned short*)((char*)za + ZA_OFF(r1, nc1)) = f2bf(fmaxf(c11[reg] + bB, 0.f));
        }
    }
    STAGE_WT(Wt + DIM * DIM);                   // W2^T
    __syncthreads();

    // ---- GEMM2 ----
    c00 = {0.f, 0.f, 0.f, 0.f}; c01 = {0.f, 0.f, 0.f, 0.f};
    c10 = {0.f, 0.f, 0.f, 0.f}; c11 = {0.f, 0.f, 0.f, 0.f};
    MFMA_GEMM();

    // ---- epilogue: bias2, z write (fp32), BN stats (shfl-reduce) ----
    {
        const float bA = b2[nc0], bB = b2[nc1];
        float sA = 0.f, qA = 0.f, sB = 0.f, qB = 0.f;
        #pragma unroll
        for (int reg = 0; reg < 4; ++reg) {
            int g0 = row0 + rb + reg;
            if (g0 < NN) {
                float v0 = c00[reg] + bA;
                float v1 = c01[reg] + bB;
                z[(size_t)g0 * DIM + nc0] = v0;
                z[(size_t)g0 * DIM + nc1] = v1;
                sA += v0; qA += v0 * v0;
                sB += v1; qB += v1 * v1;
            }
            int g1 = row0 + 16 + rb + reg;
            if (g1 < NN) {
                float v0 = c10[reg] + bA;
                float v1 = c11[reg] + bB;
                z[(size_t)g1 * DIM + nc0] = v0;
                z[(size_t)g1 * DIM + nc1] = v1;
                sA += v0; qA += v0 * v0;
                sB += v1; qB += v1 * v1;
            }
        }
        // reduce over the 4 row-groups (bits 4,5 of lane); cols untouched
        sA += __shfl_xor(sA, 16); sA += __shfl_xor(sA, 32);
        qA += __shfl_xor(qA, 16); qA += __shfl_xor(qA, 32);
        sB += __shfl_xor(sB, 16); sB += __shfl_xor(sB, 32);
        qB += __shfl_xor(qB, 16); qB += __shfl_xor(qB, 32);
        if (lane < 16) {
            atomicAdd(&bnsum[nc0], sA);
            atomicAdd(&bnsq[nc0], qA);
            atomicAdd(&bnsum[nc1], sB);
            atomicAdd(&bnsq[nc1], qB);
        }
    }
}

// ------------- final FC with fused last-layer norm (per-lane sc/sh) ----
__global__ __launch_bounds__(256) void k_fc(const float* __restrict__ z,
                                            const float* __restrict__ bnsum,
                                            const float* __restrict__ bnsq,
                                            const float* __restrict__ gamma,
                                            const float* __restrict__ beta,
                                            const float* __restrict__ fc_w,
                                            const float* __restrict__ fc_b,
                                            float* __restrict__ out) {
    int wid  = (blockIdx.x * 256 + threadIdx.x) >> 6;
    int lane = threadIdx.x & 63;
    if (wid >= NN) return;
    const int j0 = lane * 2;
    const float invN = 1.0f / (float)NN;
    float mu0 = bnsum[j0] * invN;
    float mu1 = bnsum[j0 + 1] * invN;
    float k0 = rsqrtf(bnsq[j0] * invN - mu0 * mu0 + BN_EPS) * gamma[j0];
    float k1 = rsqrtf(bnsq[j0 + 1] * invN - mu1 * mu1 + BN_EPS) * gamma[j0 + 1];
    float sh0 = beta[j0] - mu0 * k0;
    float sh1 = beta[j0 + 1] - mu1 * k1;

    float2 v = *(const float2*)&z[(size_t)wid * DIM + lane * 2];
    v.x = fmaxf(fmaf(v.x, k0, sh0), 0.f);
    v.y = fmaxf(fmaf(v.y, k1, sh1), 0.f);
    float2 wv = *(const float2*)&fc_w[lane * 2];
    float s = v.x * wv.x + v.y * wv.y;
    #pragma unroll
    for (int o = 32; o >= 1; o >>= 1) s += __shfl_down(s, o);
    if (lane == 0) out[wid] = s + fc_b[0];
}

// -------------------------------------------------------------- launch ----
extern "C" void kernel_launch(void* const* d_in, const int* in_sizes, int n_in,
                              void* d_out, int out_size, void* d_ws, size_t ws_size,
                              hipStream_t stream) {
    const float* x     = (const float*)d_in[0];
    const int*   src   = (const int*)d_in[1];          // edge_index[0]
    const int*   dst   = ((const int*)d_in[1]) + NE;   // edge_index[1]
    const float* W1    = (const float*)d_in[2];
    const float* b1    = (const float*)d_in[3];
    const float* W2    = (const float*)d_in[4];
    const float* b2    = (const float*)d_in[5];
    const float* gamma = (const float*)d_in[6];
    const float* beta  = (const float*)d_in[7];
    const float* fc_w  = (const float*)d_in[8];
    const float* fc_b  = (const float*)d_in[9];
    float* out = (float*)d_out;

    // workspace carve (16B aligned chunks)
    char* ws = (char*)d_ws;
    size_t o = 0;
    auto carve = [&](size_t bytes) {
        char* p = ws + o;
        o += (bytes + 15) & ~(size_t)15;
        return p;
    };
    int*   deg     = (int*)carve(NN * 4);
    int*   off     = (int*)carve((NN + 1) * 4);
    int*   cur     = (int*)carve(NN * 4);
    int*   csr     = (int*)carve(NE * 4);
    int*   part    = (int*)carve(NN * 4);
    int*   bsum    = (int*)carve(NSCAN * 4);
    int*   boff    = (int*)carve(NSCAN * 4);
    float* bnstats = (float*)carve(LAYERS * 2 * DIM * 4);  // [sum(3x128) | sq(3x128)]
    unsigned short* wtg = (unsigned short*)carve(LAYERS * 2 * DIM * DIM * 2); // bf16 W^T
    float* zA      = (float*)carve((size_t)NN * DIM * 4);
    float* zB      = (float*)carve((size_t)NN * DIM * 4);

    // ---- CSR build + W conversion (once per call) ----
    k_init<<<(NN + 255) / 256, 256, 0, stream>>>(deg, bnstats);
    k_wconv<<<(LAYERS * 2 * DIM * DIM + 255) / 256, 256, 0, stream>>>(W1, W2, wtg);
    k_hist<<<(NE + 255) / 256, 256, 0, stream>>>(dst, deg);
    k_scan1<<<NSCAN, 1024, 0, stream>>>(deg, part, bsum);
    k_scan2<<<1, 64, 0, stream>>>(bsum, boff);
    k_scan3<<<(NN + 255) / 256, 256, 0, stream>>>(part, boff, off, cur);
    k_fill<<<(NE + 255) / 256, 256, 0, stream>>>(src, dst, cur, csr);

    // ---- layers: agg(norm-fused, fp32) -> mfma mlp(in-place) ----
    const int nblk_mlp = (NN + TM - 1) / TM;
    const int nblk_agg = (NN * 64 + 255) / 256;
    float* zbuf[2] = {zA, zB};
    for (int l = 0; l < LAYERS; ++l) {
        const float* hin = (l == 0) ? x : zbuf[(l + 1) & 1];
        float* zo = zbuf[l & 1];
        float* sum_l = bnstats + l * DIM;
        float* sq_l  = bnstats + LAYERS * DIM + l * DIM;
        const float* sum_p = bnstats + (l - 1) * DIM;
        const float* sq_p  = bnstats + LAYERS * DIM + (l - 1) * DIM;
        if (l == 0)
            k_agg<0><<<nblk_agg, 256, 0, stream>>>(hin, nullptr, nullptr, nullptr,
                                                   nullptr, off, csr, zo);
        else
            k_agg<1><<<nblk_agg, 256, 0, stream>>>(hin, sum_p, sq_p,
                                                   gamma + (l - 1) * DIM,
                                                   beta + (l - 1) * DIM,
                                                   off, csr, zo);
        k_mlp<<<nblk_mlp, 256, 0, stream>>>(zo,
                                            wtg + (size_t)l * 2 * DIM * DIM,
                                            b1 + l * DIM, b2 + l * DIM,
                                            sum_l, sq_l);
    }

    // ---- final FC (fused last norm) ----
    k_fc<<<(NN * 64 + 255) / 256, 256, 0, stream>>>(zbuf[(LAYERS + 1) & 1],
                                                    bnstats + (LAYERS - 1) * DIM,
                                                    bnstats + (2 * LAYERS - 1) * DIM,
                                                    gamma + (LAYERS - 1) * DIM,
                                                    beta + (LAYERS - 1) * DIM,
                                                    fc_w, fc_b, out);
}